// Round 1
// baseline (200.239 us; speedup 1.0000x reference)
//
#include <hip/hip_runtime.h>

#define NPTS  (4 * 32768)   // B*G
#define GPTS  32768         // G (points per batch)
#define HH    256
#define WW    256
#define CIN_  64
#define COUT_ 64

// ---- sigmoid emulating the reference f32 pipeline -------------------------
// ref: s = 1/(1 + exp(-clip(x, -9.21, 9.21))) computed in float32.
// exp via double (≈correctly rounded f32 exp after cast), add/div in f32.
__device__ __forceinline__ float sigf(float x) {
    x = fminf(fmaxf(x, -9.21f), 9.21f);
    float t = (float)exp(-(double)x);
    return 1.0f / (1.0f + t);
}

// ---- kernel 1: sigmoid + global per-coordinate min (bit-pattern atomicMin) -
__global__ __launch_bounds__(256) void k_sigmin(const float* __restrict__ anchor,
                                                float* __restrict__ s0a,
                                                float* __restrict__ s1a,
                                                unsigned* __restrict__ mins) {
    int i = blockIdx.x * 256 + threadIdx.x;
    float2 a = ((const float2*)anchor)[i];
    float s0 = sigf(a.x);
    float s1 = sigf(a.y);
    s0a[i] = s0;
    s1a[i] = s1;
    // wave-level min reduce (64 lanes)
    float m0 = s0, m1 = s1;
    #pragma unroll
    for (int off = 32; off; off >>= 1) {
        m0 = fminf(m0, __shfl_down(m0, off));
        m1 = fminf(m1, __shfl_down(m1, off));
    }
    if ((threadIdx.x & 63) == 0) {
        // sigmoid outputs are positive -> float order == uint bit order
        atomicMin(&mins[0], __float_as_uint(m0));
        atomicMin(&mins[1], __float_as_uint(m1));
    }
}

// ---- kernel 2: cell index + rulebook scatter (max point id wins) -----------
__global__ __launch_bounds__(256) void k_grid(const float* __restrict__ s0a,
                                              const float* __restrict__ s1a,
                                              const unsigned* __restrict__ mins,
                                              int* __restrict__ pidx,
                                              int* __restrict__ grid) {
    int i = blockIdx.x * 256 + threadIdx.x;
    float m0 = __uint_as_float(mins[0]);
    float m1 = __uint_as_float(mins[1]);
    // (s - min) * 256.0f  ==  (s - min) / (1/256) bit-exactly (scale by 2^8)
    int iy = (int)((s0a[i] - m0) * 256.0f);
    int ix = (int)((s1a[i] - m1) * 256.0f);
    pidx[i] = (iy << 8) | ix;
    int b = i >> 15;                       // i / G
    atomicMax(&grid[(b << 16) + (iy << 8) + ix], i);
}

// ---- kernel 3: gather-conv ---------------------------------------------
// lane = point (64 points per wave). Block = 128 threads = 2 waves:
// wave 0 computes cout[0:32), wave 1 computes cout[32:64) for the same 64 pts.
// W is read via wave-uniform address (readfirstlane) -> scalar loads (SGPR),
// features gathered per-lane as float4 -> v_fmac_f32 with SGPR weight operand.
__global__ __launch_bounds__(128) void k_conv(const float* __restrict__ feats,
                                              const float* __restrict__ W,
                                              const int* __restrict__ pidx,
                                              const int* __restrict__ grid,
                                              float* __restrict__ out) {
    const int lane = threadIdx.x & 63;
    const int half = threadIdx.x >> 6;                       // 0 or 1
    const int p    = (blockIdx.x << 6) + lane;               // point id
    const int c0   = __builtin_amdgcn_readfirstlane(half << 5); // uniform cout base

    const int pk = pidx[p];
    const int iy = pk >> 8;
    const int ix = pk & 255;
    const int* gb = grid + ((p >> 15) << 16);                // this point's batch grid

    float acc[32];
    #pragma unroll
    for (int c = 0; c < 32; ++c) acc[c] = 0.0f;

    #pragma unroll 1
    for (int tap = 0; tap < 9; ++tap) {
        const int dy = tap / 3 - 1;
        const int dx = tap % 3 - 1;
        const int ny = iy + dy;
        const int nx = ix + dx;
        int nid = -1;
        if ((unsigned)ny < 256u && (unsigned)nx < 256u)
            nid = gb[(ny << 8) + nx];
        if (nid >= 0) {
            const float4* frow = (const float4*)(feats + ((long)nid << 6));
            const float* wt = W + (tap << 12) + c0;          // uniform
            #pragma unroll
            for (int k4 = 0; k4 < 16; ++k4) {
                float4 f = frow[k4];
                const float* wr = wt + (k4 << 8);            // k4*4*64, uniform
                float fj[4] = {f.x, f.y, f.z, f.w};
                #pragma unroll
                for (int j = 0; j < 4; ++j) {
                    #pragma unroll
                    for (int c = 0; c < 32; ++c)
                        acc[c] = fmaf(fj[j], wr[(j << 6) + c], acc[c]);
                }
            }
        }
    }

    float4* op = (float4*)(out + ((long)p << 6) + c0);
    #pragma unroll
    for (int c4 = 0; c4 < 8; ++c4)
        op[c4] = make_float4(acc[4 * c4 + 0], acc[4 * c4 + 1],
                             acc[4 * c4 + 2], acc[4 * c4 + 3]);
}

extern "C" void kernel_launch(void* const* d_in, const int* in_sizes, int n_in,
                              void* d_out, int out_size, void* d_ws, size_t ws_size,
                              hipStream_t stream) {
    const float* inst   = (const float*)d_in[0]; // (B,G,64)
    const float* anchor = (const float*)d_in[1]; // (B,G,2)
    const float* W      = (const float*)d_in[2]; // (3,3,64,64)
    float* out = (float*)d_out;

    char* ws = (char*)d_ws;
    unsigned* mins = (unsigned*)ws;                    // 2 x u32 (+pad)
    float* s0a = (float*)(ws + 256);                   // N floats
    float* s1a = s0a + NPTS;                           // N floats
    int*   pidx = (int*)(s1a + NPTS);                  // N ints (iy<<8|ix)
    int*   grid = pidx + NPTS;                         // 4*256*256 ints

    hipMemsetAsync(mins, 0xFF, 8, stream);                       // +inf-ish bits
    hipMemsetAsync(grid, 0xFF, (size_t)4 * 65536 * 4, stream);   // -1

    k_sigmin<<<NPTS / 256, 256, 0, stream>>>(anchor, s0a, s1a, mins);
    k_grid  <<<NPTS / 256, 256, 0, stream>>>(s0a, s1a, mins, pidx, grid);
    k_conv  <<<NPTS / 64, 128, 0, stream>>>(inst, W, pidx, grid, out);
}

// Round 2
// 186.773 us; speedup vs baseline: 1.0721x; 1.0721x over previous
//
#include <hip/hip_runtime.h>

#define NPTS  (4 * 32768)   // B*G
#define GPTS  32768         // G (points per batch)
#define HH    256
#define WW    256
#define CIN_  64
#define COUT_ 64

// ---- sigmoid emulating the reference f32 pipeline -------------------------
__device__ __forceinline__ float sigf(float x) {
    x = fminf(fmaxf(x, -9.21f), 9.21f);
    float t = (float)exp(-(double)x);
    return 1.0f / (1.0f + t);
}

// ---- kernel 1: sigmoid + global per-coordinate min (bit-pattern atomicMin) -
__global__ __launch_bounds__(256) void k_sigmin(const float* __restrict__ anchor,
                                                float* __restrict__ s0a,
                                                float* __restrict__ s1a,
                                                unsigned* __restrict__ mins) {
    int i = blockIdx.x * 256 + threadIdx.x;
    float2 a = ((const float2*)anchor)[i];
    float s0 = sigf(a.x);
    float s1 = sigf(a.y);
    s0a[i] = s0;
    s1a[i] = s1;
    float m0 = s0, m1 = s1;
    #pragma unroll
    for (int off = 32; off; off >>= 1) {
        m0 = fminf(m0, __shfl_down(m0, off));
        m1 = fminf(m1, __shfl_down(m1, off));
    }
    if ((threadIdx.x & 63) == 0) {
        atomicMin(&mins[0], __float_as_uint(m0));   // sigmoid > 0: uint order == float order
        atomicMin(&mins[1], __float_as_uint(m1));
    }
}

// ---- kernel 2: cell index + rulebook scatter (max point id wins) -----------
__global__ __launch_bounds__(256) void k_grid(const float* __restrict__ s0a,
                                              const float* __restrict__ s1a,
                                              const unsigned* __restrict__ mins,
                                              int* __restrict__ pidx,
                                              int* __restrict__ grid) {
    int i = blockIdx.x * 256 + threadIdx.x;
    float m0 = __uint_as_float(mins[0]);
    float m1 = __uint_as_float(mins[1]);
    int iy = (int)((s0a[i] - m0) * 256.0f);
    int ix = (int)((s1a[i] - m1) * 256.0f);
    pidx[i] = (iy << 8) | ix;
    int b = i >> 15;
    atomicMax(&grid[(b << 16) + (iy << 8) + ix], i);
}

// ---- kernel 3: gather-conv -------------------------------------------------
// Block = 256 thr = 4 waves, all covering the same 64 points (lane = point).
// Wave w computes couts [16w, 16w+16) -> 16 accumulators/lane, VGPR ~40,
// grid 2048 blocks * 4 waves = 8192 waves = 32/CU (100% occupancy cap).
// All 9 nid gathers hoisted so their latency overlaps.
__global__ __launch_bounds__(256, 8) void k_conv(const float* __restrict__ feats,
                                                 const float* __restrict__ W,
                                                 const int* __restrict__ pidx,
                                                 const int* __restrict__ grid,
                                                 float* __restrict__ out) {
    const int lane = threadIdx.x & 63;
    const int wv   = threadIdx.x >> 6;                          // 0..3
    const int p    = (blockIdx.x << 6) + lane;                  // point id
    const int c0   = __builtin_amdgcn_readfirstlane(wv << 4);   // uniform cout base

    const int pk = pidx[p];
    const int iy = pk >> 8;
    const int ix = pk & 255;
    const int* gb = grid + ((p >> 15) << 16);

    // all 9 neighbor-id gathers in flight together
    int nid[9];
    #pragma unroll
    for (int tap = 0; tap < 9; ++tap) {
        const int ny = iy + tap / 3 - 1;
        const int nx = ix + tap % 3 - 1;
        nid[tap] = ((unsigned)ny < 256u && (unsigned)nx < 256u) ? gb[(ny << 8) + nx] : -1;
    }

    float acc[16];
    #pragma unroll
    for (int c = 0; c < 16; ++c) acc[c] = 0.0f;

    #pragma unroll 1
    for (int tap = 0; tap < 9; ++tap) {
        const int n = nid[tap];
        if (n >= 0) {
            const float4* frow = (const float4*)(feats + ((long)n << 6));
            const float* wt = W + (tap << 12) + c0;              // uniform
            #pragma unroll
            for (int k4 = 0; k4 < 16; ++k4) {
                float4 f = frow[k4];
                const float* wr = wt + (k4 << 8);                // uniform
                float fj[4] = {f.x, f.y, f.z, f.w};
                #pragma unroll
                for (int j = 0; j < 4; ++j) {
                    #pragma unroll
                    for (int c = 0; c < 16; ++c)
                        acc[c] = fmaf(fj[j], wr[(j << 6) + c], acc[c]);
                }
            }
        }
    }

    float4* op = (float4*)(out + ((long)p << 6) + c0);
    #pragma unroll
    for (int c4 = 0; c4 < 4; ++c4)
        op[c4] = make_float4(acc[4 * c4 + 0], acc[4 * c4 + 1],
                             acc[4 * c4 + 2], acc[4 * c4 + 3]);
}

extern "C" void kernel_launch(void* const* d_in, const int* in_sizes, int n_in,
                              void* d_out, int out_size, void* d_ws, size_t ws_size,
                              hipStream_t stream) {
    const float* inst   = (const float*)d_in[0]; // (B,G,64)
    const float* anchor = (const float*)d_in[1]; // (B,G,2)
    const float* W      = (const float*)d_in[2]; // (3,3,64,64)
    float* out = (float*)d_out;

    char* ws = (char*)d_ws;
    unsigned* mins = (unsigned*)ws;                    // 2 x u32 (+pad)
    float* s0a = (float*)(ws + 256);                   // N floats
    float* s1a = s0a + NPTS;                           // N floats
    int*   pidx = (int*)(s1a + NPTS);                  // N ints (iy<<8|ix)
    int*   grid = pidx + NPTS;                         // 4*256*256 ints

    hipMemsetAsync(mins, 0xFF, 8, stream);
    hipMemsetAsync(grid, 0xFF, (size_t)4 * 65536 * 4, stream);

    k_sigmin<<<NPTS / 256, 256, 0, stream>>>(anchor, s0a, s1a, mins);
    k_grid  <<<NPTS / 256, 256, 0, stream>>>(s0a, s1a, mins, pidx, grid);
    k_conv  <<<NPTS / 64, 256, 0, stream>>>(inst, W, pidx, grid, out);
}

// Round 3
// 126.144 us; speedup vs baseline: 1.5874x; 1.4806x over previous
//
#include <hip/hip_runtime.h>

#define NPTS  131072        // B*G
#define GPTS  32768         // G

typedef __attribute__((ext_vector_type(8)))  short short8v;
typedef __attribute__((ext_vector_type(16))) float f32x16;

// ---- sigmoid emulating the reference f32 pipeline (bit-faithful enough) ---
__device__ __forceinline__ float sigf(float x) {
    x = fminf(fmaxf(x, -9.21f), 9.21f);
    float t = (float)exp(-(double)x);
    return 1.0f / (1.0f + t);
}
__device__ __forceinline__ unsigned short bf_rne(float x) {
    unsigned u = __float_as_uint(x);
    return (unsigned short)((u + 0x7FFF + ((u >> 16) & 1)) >> 16);
}
__device__ __forceinline__ float bf_up(unsigned short h) {
    return __uint_as_float(((unsigned)h) << 16);
}

// ---- fused prep: feats->bf16 rows (+zero row) | W->B-frag pack | sigmoid+min
// blocks [0,4097): cvt; [4097,4115): wpack; [4115,4627): sigmin
#define CVT_B 4097
#define WPK_B 18
#define SIG_B 512
__global__ __launch_bounds__(256) void k_prep(const float* __restrict__ feats,
                                              const float* __restrict__ anchor,
                                              const float* __restrict__ W,
                                              unsigned short* __restrict__ fb,
                                              unsigned short* __restrict__ bpk,
                                              float* __restrict__ s0a,
                                              float* __restrict__ s1a,
                                              unsigned* __restrict__ mins) {
    const int bid = blockIdx.x;
    if (bid < CVT_B) {
        // convert 8 floats -> 8 bf16 per thread; row NPTS is all zeros
        long e = ((long)bid * 256 + threadIdx.x) * 8;
        if (e < (long)NPTS * 64) {
            float4 f0 = ((const float4*)(feats + e))[0];
            float4 f1 = ((const float4*)(feats + e))[1];
            short8v o;
            o[0] = bf_rne(f0.x); o[1] = bf_rne(f0.y); o[2] = bf_rne(f0.z); o[3] = bf_rne(f0.w);
            o[4] = bf_rne(f1.x); o[5] = bf_rne(f1.y); o[6] = bf_rne(f1.z); o[7] = bf_rne(f1.w);
            *(short8v*)(fb + e) = o;
        } else if (e < (long)(NPTS + 1) * 64) {
            short8v z = {};
            *(short8v*)(fb + e) = z;
        }
    } else if (bid < CVT_B + WPK_B) {
        // pack W[t][k][c] into 32x32x16 B-fragments, hi then lo (4608 frags each)
        int tid = (bid - CVT_B) * 256 + threadIdx.x;   // [0,4608)
        if (tid < 4608) {
            int l  = tid & 63;
            int q  = tid >> 6;        // 0..71
            int nt = q & 1;
            int ks = (q >> 1) & 3;
            int t  = q >> 3;          // 0..8
            int n  = nt * 32 + (l & 31);
            int kb = ks * 16 + (l >> 5) * 8;
            short8v hi, lo;
            #pragma unroll
            for (int j = 0; j < 8; ++j) {
                float w = W[(t * 64 + kb + j) * 64 + n];
                unsigned short h = bf_rne(w);
                hi[j] = h;
                lo[j] = bf_rne(w - bf_up(h));
            }
            long e = ((long)(t * 8 + ks * 2 + nt) * 64 + l) * 8;
            *(short8v*)(bpk + e) = hi;
            *(short8v*)(bpk + (long)4608 * 8 + e) = lo;
        }
    } else {
        // sigmoid + global min (bit-pattern atomicMin; sigmoid > 0)
        int i = (bid - CVT_B - WPK_B) * 256 + threadIdx.x;   // [0,131072)
        float2 a = ((const float2*)anchor)[i];
        float s0 = sigf(a.x);
        float s1 = sigf(a.y);
        s0a[i] = s0;
        s1a[i] = s1;
        float m0 = s0, m1 = s1;
        #pragma unroll
        for (int off = 32; off; off >>= 1) {
            m0 = fminf(m0, __shfl_down(m0, off));
            m1 = fminf(m1, __shfl_down(m1, off));
        }
        if ((threadIdx.x & 63) == 0) {
            atomicMin(&mins[0], __float_as_uint(m0));
            atomicMin(&mins[1], __float_as_uint(m1));
        }
    }
}

// ---- cell index + rulebook scatter (max point id wins) --------------------
__global__ __launch_bounds__(256) void k_grid(const float* __restrict__ s0a,
                                              const float* __restrict__ s1a,
                                              const unsigned* __restrict__ mins,
                                              int* __restrict__ pidx,
                                              int* __restrict__ grid) {
    int i = blockIdx.x * 256 + threadIdx.x;
    float m0 = __uint_as_float(mins[0]);
    float m1 = __uint_as_float(mins[1]);
    int iy = (int)((s0a[i] - m0) * 256.0f);
    int ix = (int)((s1a[i] - m1) * 256.0f);
    pidx[i] = (iy << 8) | ix;
    int b = i >> 15;
    atomicMax(&grid[(b << 16) + (iy << 8) + ix], i);
}

// ---- MFMA conv: wave = 32 points x 64 couts, dense over 9 taps ------------
// A-frag (32x32x16): lane l holds A[row=l&31][k = ks*16 + (l>>5)*8 + j]
//   -> 16B contiguous load from gathered bf16 row (zero row for invalid taps)
// B-frag: pre-packed. C/D: col=lane&31, row=(reg&3)+8*(reg>>2)+4*(lane>>5)  [HW-verified]
__global__ __launch_bounds__(256, 4) void k_mconv(const unsigned short* __restrict__ fb,
                                                  const unsigned short* __restrict__ bpk,
                                                  const int* __restrict__ pidx,
                                                  const int* __restrict__ grid,
                                                  float* __restrict__ out) {
    const int lane  = threadIdx.x & 63;
    const int wv    = threadIdx.x >> 6;
    const int pbase = (blockIdx.x << 7) + (wv << 5);   // 32 points per wave
    const int prow  = lane & 31;
    const int khalf = lane >> 5;                       // 0..1
    const int p     = pbase + prow;

    const int pk = pidx[p];
    const int iy = pk >> 8;
    const int ix = pk & 255;
    const int* gb = grid + ((p >> 15) << 16);

    const short8v* bq = (const short8v*)bpk + lane;    // + frag-index*64 below

    f32x16 acc0, acc1;
    #pragma unroll
    for (int r = 0; r < 16; ++r) { acc0[r] = 0.0f; acc1[r] = 0.0f; }

    // nid gather pipelined one tap ahead (scalars only; no runtime-indexed arrays)
    int nidc;
    {
        int ny = iy - 1, nx = ix - 1;
        int n = ((unsigned)ny < 256u && (unsigned)nx < 256u) ? gb[(ny << 8) + nx] : -1;
        nidc = (n < 0) ? NPTS : n;
    }

    #pragma unroll 1
    for (int t = 0; t < 9; ++t) {
        int nidn = NPTS;
        if (t < 8) {
            int tn = t + 1;
            int ny = iy + tn / 3 - 1, nx = ix + tn % 3 - 1;
            int n = ((unsigned)ny < 256u && (unsigned)nx < 256u) ? gb[(ny << 8) + nx] : -1;
            nidn = (n < 0) ? NPTS : n;
        }

        const short8v* arow = (const short8v*)(fb + ((long)nidc << 6));
        short8v aa0 = arow[khalf];
        short8v aa1 = arow[2 + khalf];
        short8v aa2 = arow[4 + khalf];
        short8v aa3 = arow[6 + khalf];

        const short8v* bt = bq + (t << 9);             // 8 frags * 64 lanes per tap
        #pragma unroll
        for (int ks = 0; ks < 4; ++ks) {
            short8v a = (ks == 0) ? aa0 : (ks == 1) ? aa1 : (ks == 2) ? aa2 : aa3;
            acc0 = __builtin_amdgcn_mfma_f32_32x32x16_bf16(a, bt[(ks * 2 + 0) * 64], acc0, 0, 0, 0);
            acc1 = __builtin_amdgcn_mfma_f32_32x32x16_bf16(a, bt[(ks * 2 + 1) * 64], acc1, 0, 0, 0);
            acc0 = __builtin_amdgcn_mfma_f32_32x32x16_bf16(a, bt[4608 + (ks * 2 + 0) * 64], acc0, 0, 0, 0);
            acc1 = __builtin_amdgcn_mfma_f32_32x32x16_bf16(a, bt[4608 + (ks * 2 + 1) * 64], acc1, 0, 0, 0);
        }
        nidc = nidn;
    }

    // epilogue: D[row][col] -> out[point][cout]
    #pragma unroll
    for (int r = 0; r < 16; ++r) {
        int orow = pbase + (r & 3) + ((r >> 2) << 3) + (khalf << 2);
        out[(long)orow * 64 + prow]      = acc0[r];
        out[(long)orow * 64 + 32 + prow] = acc1[r];
    }
}

extern "C" void kernel_launch(void* const* d_in, const int* in_sizes, int n_in,
                              void* d_out, int out_size, void* d_ws, size_t ws_size,
                              hipStream_t stream) {
    const float* inst   = (const float*)d_in[0]; // (B,G,64)
    const float* anchor = (const float*)d_in[1]; // (B,G,2)
    const float* W      = (const float*)d_in[2]; // (3,3,64,64)
    float* out = (float*)d_out;

    char* ws = (char*)d_ws;
    unsigned*       mins = (unsigned*)ws;                       // 256 B
    float*          s0a  = (float*)(ws + 256);                  // 512 KB
    float*          s1a  = (float*)(ws + 256 + 524288);         // 512 KB
    int*            pidx = (int*)(ws + 256 + 2 * 524288);       // 512 KB
    int*            grd  = (int*)(ws + 256 + 3 * 524288);       // 1 MB
    unsigned short* fb   = (unsigned short*)(ws + 2621696);     // (N+1)*64 bf16 = 16.8 MB
    unsigned short* bpk  = (unsigned short*)(ws + 19399040);    // 147456 B  (hi+lo frags)

    hipMemsetAsync(mins, 0xFF, 8, stream);
    hipMemsetAsync(grd, 0xFF, (size_t)4 * 65536 * 4, stream);

    k_prep <<<CVT_B + WPK_B + SIG_B, 256, 0, stream>>>(inst, anchor, W, fb, bpk, s0a, s1a, mins);
    k_grid <<<512, 256, 0, stream>>>(s0a, s1a, mins, pidx, grd);
    k_mconv<<<1024, 256, 0, stream>>>(fb, bpk, pidx, grd, out);
}

// Round 4
// 65.043 us; speedup vs baseline: 3.0785x; 1.9394x over previous
//
#include <hip/hip_runtime.h>

#define NPTS  131072        // B*G
#define GPTS  32768         // G

typedef __attribute__((ext_vector_type(4)))  _Float16 half4v;
typedef __attribute__((ext_vector_type(8)))  _Float16 half8v;
typedef __attribute__((ext_vector_type(16))) float    f32x16;

// ---- sigmoid emulating the reference f32 pipeline (bit-faithful) ----------
__device__ __forceinline__ float sigf(float x) {
    x = fminf(fmaxf(x, -9.21f), 9.21f);
    float t = (float)exp(-(double)x);
    return 1.0f / (1.0f + t);
}

// ---- feats f32 -> f16 rows (+1 zero row) ----------------------------------
__global__ __launch_bounds__(256) void k_cvt(const float* __restrict__ in,
                                             _Float16* __restrict__ fb) {
    if (blockIdx.x == 0 && threadIdx.x < 8) {
        half8v z = {};
        *(half8v*)(fb + (long)NPTS * 64 + threadIdx.x * 8) = z;
    }
    int tid = blockIdx.x * 256 + threadIdx.x;
    #pragma unroll
    for (int r = 0; r < 4; ++r) {
        long i = tid + (long)r * 524288;            // 2048*256 threads, 4 float4 each
        float4 f = ((const float4*)in)[i];
        half4v o = {(_Float16)f.x, (_Float16)f.y, (_Float16)f.z, (_Float16)f.w};
        *(half4v*)(fb + i * 4) = o;
    }
}

// ---- W -> 32x32x16 f16 B-fragments (72 frags, single pass) ----------------
// frag q = t*8 + ks*2 + nt; lane l holds B[k=ks*16+(l>>5)*8+j][n=nt*32+(l&31)]
__global__ __launch_bounds__(256) void k_wpack(const float* __restrict__ W,
                                               _Float16* __restrict__ bpk) {
    int tid = blockIdx.x * 256 + threadIdx.x;
    if (tid >= 4608) return;
    int l  = tid & 63;
    int q  = tid >> 6;                  // 0..71
    int nt = q & 1;
    int ks = (q >> 1) & 3;
    int t  = q >> 3;                    // 0..8
    int n  = nt * 32 + (l & 31);
    int kb = ks * 16 + (l >> 5) * 8;
    half8v v;
    #pragma unroll
    for (int j = 0; j < 8; ++j)
        v[j] = (_Float16)W[(t * 64 + kb + j) * 64 + n];
    ((half8v*)bpk)[q * 64 + l] = v;
}

// ---- sigmoid + per-block min (NO global atomics) --------------------------
__global__ __launch_bounds__(256) void k_sig(const float* __restrict__ anchor,
                                             float* __restrict__ s0a,
                                             float* __restrict__ s1a,
                                             float2* __restrict__ blockmin) {
    __shared__ float red[8];
    int tid = blockIdx.x * 256 + threadIdx.x;
    float m0 = 1e30f, m1 = 1e30f;
    #pragma unroll
    for (int r = 0; r < 2; ++r) {
        int i = tid + r * 65536;
        float2 a = ((const float2*)anchor)[i];
        float s0 = sigf(a.x);
        float s1 = sigf(a.y);
        s0a[i] = s0;
        s1a[i] = s1;
        m0 = fminf(m0, s0);
        m1 = fminf(m1, s1);
    }
    #pragma unroll
    for (int off = 32; off; off >>= 1) {
        m0 = fminf(m0, __shfl_down(m0, off));
        m1 = fminf(m1, __shfl_down(m1, off));
    }
    int wv = threadIdx.x >> 6;
    if ((threadIdx.x & 63) == 0) { red[wv * 2] = m0; red[wv * 2 + 1] = m1; }
    __syncthreads();
    if (threadIdx.x == 0) {
        float a0 = fminf(fminf(red[0], red[2]), fminf(red[4], red[6]));
        float a1 = fminf(fminf(red[1], red[3]), fminf(red[5], red[7]));
        blockmin[blockIdx.x] = make_float2(a0, a1);
    }
}

// ---- cell index + rulebook scatter (max id wins); min-reduce folded in ----
__global__ __launch_bounds__(256) void k_grid(const float* __restrict__ s0a,
                                              const float* __restrict__ s1a,
                                              const float2* __restrict__ blockmin,
                                              int* __restrict__ pidx,
                                              int* __restrict__ grid) {
    __shared__ float red[8];
    float2 bm = blockmin[threadIdx.x];              // 256 entries
    float m0 = bm.x, m1 = bm.y;
    #pragma unroll
    for (int off = 32; off; off >>= 1) {
        m0 = fminf(m0, __shfl_down(m0, off));
        m1 = fminf(m1, __shfl_down(m1, off));
    }
    int wv = threadIdx.x >> 6;
    if ((threadIdx.x & 63) == 0) { red[wv * 2] = m0; red[wv * 2 + 1] = m1; }
    __syncthreads();
    m0 = fminf(fminf(red[0], red[2]), fminf(red[4], red[6]));
    m1 = fminf(fminf(red[1], red[3]), fminf(red[5], red[7]));

    int i = blockIdx.x * 256 + threadIdx.x;
    int iy = (int)((s0a[i] - m0) * 256.0f);
    int ix = (int)((s1a[i] - m1) * 256.0f);
    pidx[i] = (iy << 8) | ix;
    int b = i >> 15;
    atomicMax(&grid[(b << 16) + (iy << 8) + ix], i);
}

// ---- MFMA conv: wave = 32 points x 64 couts, f16 single pass --------------
// A-frag: lane l holds A[row=l&31][k=ks*16+(l>>5)*8+j] -> 16B load from row
// C/D: col=lane&31, row=(reg&3)+8*(reg>>2)+4*(lane>>5)   [HW-verified]
__global__ __launch_bounds__(256, 4) void k_mconv(const _Float16* __restrict__ fb,
                                                  const _Float16* __restrict__ bpk,
                                                  const int* __restrict__ pidx,
                                                  const int* __restrict__ grid,
                                                  float* __restrict__ out) {
    const int lane  = threadIdx.x & 63;
    const int wv    = threadIdx.x >> 6;
    const int pbase = (blockIdx.x << 7) + (wv << 5);
    const int prow  = lane & 31;
    const int khalf = lane >> 5;
    const int p     = pbase + prow;

    const int pk = pidx[p];
    const int iy = pk >> 8;
    const int ix = pk & 255;
    const int* gb = grid + ((p >> 15) << 16);

    int nid[9];
    #pragma unroll
    for (int t = 0; t < 9; ++t) {
        const int ny = iy + t / 3 - 1;
        const int nx = ix + t % 3 - 1;
        int n = ((unsigned)ny < 256u && (unsigned)nx < 256u) ? gb[(ny << 8) + nx] : -1;
        nid[t] = (n < 0) ? NPTS : n;               // zero row for invalid taps
    }

    const half8v* bq = (const half8v*)bpk + lane;

    f32x16 acc0, acc1;
    #pragma unroll
    for (int r = 0; r < 16; ++r) { acc0[r] = 0.0f; acc1[r] = 0.0f; }

    #pragma unroll
    for (int t = 0; t < 9; ++t) {
        const half8v* arow = (const half8v*)(fb + ((long)nid[t] << 6));
        half8v a0 = arow[khalf];
        half8v a1 = arow[2 + khalf];
        half8v a2 = arow[4 + khalf];
        half8v a3 = arow[6 + khalf];
        const half8v* bt = bq + (t << 9);          // 8 frags * 64 lanes per tap
        acc0 = __builtin_amdgcn_mfma_f32_32x32x16_f16(a0, bt[0 * 64], acc0, 0, 0, 0);
        acc1 = __builtin_amdgcn_mfma_f32_32x32x16_f16(a0, bt[1 * 64], acc1, 0, 0, 0);
        acc0 = __builtin_amdgcn_mfma_f32_32x32x16_f16(a1, bt[2 * 64], acc0, 0, 0, 0);
        acc1 = __builtin_amdgcn_mfma_f32_32x32x16_f16(a1, bt[3 * 64], acc1, 0, 0, 0);
        acc0 = __builtin_amdgcn_mfma_f32_32x32x16_f16(a2, bt[4 * 64], acc0, 0, 0, 0);
        acc1 = __builtin_amdgcn_mfma_f32_32x32x16_f16(a2, bt[5 * 64], acc1, 0, 0, 0);
        acc0 = __builtin_amdgcn_mfma_f32_32x32x16_f16(a3, bt[6 * 64], acc0, 0, 0, 0);
        acc1 = __builtin_amdgcn_mfma_f32_32x32x16_f16(a3, bt[7 * 64], acc1, 0, 0, 0);
    }

    #pragma unroll
    for (int r = 0; r < 16; ++r) {
        int orow = pbase + (r & 3) + ((r >> 2) << 3) + (khalf << 2);
        out[(long)orow * 64 + prow]      = acc0[r];
        out[(long)orow * 64 + 32 + prow] = acc1[r];
    }
}

extern "C" void kernel_launch(void* const* d_in, const int* in_sizes, int n_in,
                              void* d_out, int out_size, void* d_ws, size_t ws_size,
                              hipStream_t stream) {
    const float* inst   = (const float*)d_in[0]; // (B,G,64)
    const float* anchor = (const float*)d_in[1]; // (B,G,2)
    const float* W      = (const float*)d_in[2]; // (3,3,64,64)
    float* out = (float*)d_out;

    char* ws = (char*)d_ws;
    float*     s0a  = (float*)(ws);                      // 512 KB
    float*     s1a  = (float*)(ws + 524288);             // 512 KB
    int*       pidx = (int*)(ws + 1048576);              // 512 KB
    int*       grd  = (int*)(ws + 1572864);              // 1 MB
    float2*    bmin = (float2*)(ws + 2621440);           // 2 KB
    _Float16*  fb   = (_Float16*)(ws + 2625536);         // (N+1)*64 f16 = 16.78 MB
    _Float16*  bpk  = (_Float16*)(ws + 19402880);        // 72 KB

    hipMemsetAsync(grd, 0xFF, (size_t)4 * 65536 * 4, stream);

    k_cvt  <<<2048, 256, 0, stream>>>(inst, fb);
    k_wpack<<<18,   256, 0, stream>>>(W, bpk);
    k_sig  <<<256,  256, 0, stream>>>(anchor, s0a, s1a, bmin);
    k_grid <<<512,  256, 0, stream>>>(s0a, s1a, bmin, pidx, grd);
    k_mconv<<<1024, 256, 0, stream>>>(fb, bpk, pidx, grd, out);
}

// Round 5
// 59.723 us; speedup vs baseline: 3.3528x; 1.0891x over previous
//
#include <hip/hip_runtime.h>

#define NPTS  131072        // B*G
#define GPTS  32768         // G

typedef __attribute__((ext_vector_type(4)))  _Float16 half4v;
typedef __attribute__((ext_vector_type(8)))  _Float16 half8v;
typedef __attribute__((ext_vector_type(16))) float    f32x16;

// ---- sigmoid emulating the reference f32 pipeline (bit-faithful) ----------
__device__ __forceinline__ float sigf(float x) {
    x = fminf(fmaxf(x, -9.21f), 9.21f);
    float t = (float)exp(-(double)x);
    return 1.0f / (1.0f + t);
}

// ---- feats f32 -> f16 rows (+1 zero row) + grid clear (fused, no memset) --
__global__ __launch_bounds__(256) void k_cvt(const float* __restrict__ in,
                                             _Float16* __restrict__ fb,
                                             int* __restrict__ grd) {
    int tid = blockIdx.x * 256 + threadIdx.x;
    if (tid < 65536) {                               // clear 4*256*256 ints = 1 MB
        int4 mone = {-1, -1, -1, -1};
        ((int4*)grd)[tid] = mone;
    }
    if (blockIdx.x == 0 && threadIdx.x < 8) {
        half8v z = {};
        *(half8v*)(fb + (long)NPTS * 64 + threadIdx.x * 8) = z;
    }
    #pragma unroll
    for (int r = 0; r < 4; ++r) {
        long i = tid + (long)r * 524288;             // 2048*256 threads, 4 float4 each
        float4 f = ((const float4*)in)[i];
        half4v o = {(_Float16)f.x, (_Float16)f.y, (_Float16)f.z, (_Float16)f.w};
        *(half4v*)(fb + i * 4) = o;
    }
}

// ---- W -> 32x32x16 f16 B-fragments (72 frags, single pass) ----------------
// frag q = t*8 + ks*2 + nt; lane l holds B[k=ks*16+(l>>5)*8+j][n=nt*32+(l&31)]
__global__ __launch_bounds__(256) void k_wpack(const float* __restrict__ W,
                                               _Float16* __restrict__ bpk) {
    int tid = blockIdx.x * 256 + threadIdx.x;
    if (tid >= 4608) return;
    int l  = tid & 63;
    int q  = tid >> 6;                  // 0..71
    int nt = q & 1;
    int ks = (q >> 1) & 3;
    int t  = q >> 3;                    // 0..8
    int n  = nt * 32 + (l & 31);
    int kb = ks * 16 + (l >> 5) * 8;
    half8v v;
    #pragma unroll
    for (int j = 0; j < 8; ++j)
        v[j] = (_Float16)W[(t * 64 + kb + j) * 64 + n];
    ((half8v*)bpk)[q * 64 + l] = v;
}

// ---- sigmoid + per-block min (NO global atomics) --------------------------
__global__ __launch_bounds__(256) void k_sig(const float* __restrict__ anchor,
                                             float* __restrict__ s0a,
                                             float* __restrict__ s1a,
                                             float2* __restrict__ blockmin) {
    __shared__ float red[8];
    int tid = blockIdx.x * 256 + threadIdx.x;
    float m0 = 1e30f, m1 = 1e30f;
    #pragma unroll
    for (int r = 0; r < 2; ++r) {
        int i = tid + r * 65536;
        float2 a = ((const float2*)anchor)[i];
        float s0 = sigf(a.x);
        float s1 = sigf(a.y);
        s0a[i] = s0;
        s1a[i] = s1;
        m0 = fminf(m0, s0);
        m1 = fminf(m1, s1);
    }
    #pragma unroll
    for (int off = 32; off; off >>= 1) {
        m0 = fminf(m0, __shfl_down(m0, off));
        m1 = fminf(m1, __shfl_down(m1, off));
    }
    int wv = threadIdx.x >> 6;
    if ((threadIdx.x & 63) == 0) { red[wv * 2] = m0; red[wv * 2 + 1] = m1; }
    __syncthreads();
    if (threadIdx.x == 0) {
        float a0 = fminf(fminf(red[0], red[2]), fminf(red[4], red[6]));
        float a1 = fminf(fminf(red[1], red[3]), fminf(red[5], red[7]));
        blockmin[blockIdx.x] = make_float2(a0, a1);
    }
}

// ---- cell index + rulebook scatter (max id wins); min-reduce folded in ----
__global__ __launch_bounds__(256) void k_grid(const float* __restrict__ s0a,
                                              const float* __restrict__ s1a,
                                              const float2* __restrict__ blockmin,
                                              int* __restrict__ pidx,
                                              int* __restrict__ grid) {
    __shared__ float red[8];
    float2 bm = blockmin[threadIdx.x];              // 256 entries
    float m0 = bm.x, m1 = bm.y;
    #pragma unroll
    for (int off = 32; off; off >>= 1) {
        m0 = fminf(m0, __shfl_down(m0, off));
        m1 = fminf(m1, __shfl_down(m1, off));
    }
    int wv = threadIdx.x >> 6;
    if ((threadIdx.x & 63) == 0) { red[wv * 2] = m0; red[wv * 2 + 1] = m1; }
    __syncthreads();
    m0 = fminf(fminf(red[0], red[2]), fminf(red[4], red[6]));
    m1 = fminf(fminf(red[1], red[3]), fminf(red[5], red[7]));

    int i = blockIdx.x * 256 + threadIdx.x;
    int iy = (int)((s0a[i] - m0) * 256.0f);
    int ix = (int)((s1a[i] - m1) * 256.0f);
    pidx[i] = (iy << 8) | ix;
    int b = i >> 15;
    atomicMax(&grid[(b << 16) + (iy << 8) + ix], i);
}

// ---- MFMA conv: wave = 32 points x 64 couts, f16 single pass --------------
// A-frag: lane l holds A[row=l&31][k=ks*16+(l>>5)*8+j] -> 16B load from row
// C/D: col=lane&31, row=(reg&3)+8*(reg>>2)+4*(lane>>5)   [HW-verified]
__global__ __launch_bounds__(256, 4) void k_mconv(const _Float16* __restrict__ fb,
                                                  const _Float16* __restrict__ bpk,
                                                  const int* __restrict__ pidx,
                                                  const int* __restrict__ grid,
                                                  float* __restrict__ out) {
    const int lane  = threadIdx.x & 63;
    const int wv    = threadIdx.x >> 6;
    const int pbase = (blockIdx.x << 7) + (wv << 5);
    const int prow  = lane & 31;
    const int khalf = lane >> 5;
    const int p     = pbase + prow;

    const int pk = pidx[p];
    const int iy = pk >> 8;
    const int ix = pk & 255;
    const int* gb = grid + ((p >> 15) << 16);

    int nid[9];
    #pragma unroll
    for (int t = 0; t < 9; ++t) {
        const int ny = iy + t / 3 - 1;
        const int nx = ix + t % 3 - 1;
        int n = ((unsigned)ny < 256u && (unsigned)nx < 256u) ? gb[(ny << 8) + nx] : -1;
        nid[t] = (n < 0) ? NPTS : n;               // zero row for invalid taps
    }

    const half8v* bq = (const half8v*)bpk + lane;

    f32x16 acc0, acc1;
    #pragma unroll
    for (int r = 0; r < 16; ++r) { acc0[r] = 0.0f; acc1[r] = 0.0f; }

    #pragma unroll
    for (int t = 0; t < 9; ++t) {
        const half8v* arow = (const half8v*)(fb + ((long)nid[t] << 6));
        half8v a0 = arow[khalf];
        half8v a1 = arow[2 + khalf];
        half8v a2 = arow[4 + khalf];
        half8v a3 = arow[6 + khalf];
        const half8v* bt = bq + (t << 9);          // 8 frags * 64 lanes per tap
        acc0 = __builtin_amdgcn_mfma_f32_32x32x16_f16(a0, bt[0 * 64], acc0, 0, 0, 0);
        acc1 = __builtin_amdgcn_mfma_f32_32x32x16_f16(a0, bt[1 * 64], acc1, 0, 0, 0);
        acc0 = __builtin_amdgcn_mfma_f32_32x32x16_f16(a1, bt[2 * 64], acc0, 0, 0, 0);
        acc1 = __builtin_amdgcn_mfma_f32_32x32x16_f16(a1, bt[3 * 64], acc1, 0, 0, 0);
        acc0 = __builtin_amdgcn_mfma_f32_32x32x16_f16(a2, bt[4 * 64], acc0, 0, 0, 0);
        acc1 = __builtin_amdgcn_mfma_f32_32x32x16_f16(a2, bt[5 * 64], acc1, 0, 0, 0);
        acc0 = __builtin_amdgcn_mfma_f32_32x32x16_f16(a3, bt[6 * 64], acc0, 0, 0, 0);
        acc1 = __builtin_amdgcn_mfma_f32_32x32x16_f16(a3, bt[7 * 64], acc1, 0, 0, 0);
    }

    #pragma unroll
    for (int r = 0; r < 16; ++r) {
        int orow = pbase + (r & 3) + ((r >> 2) << 3) + (khalf << 2);
        out[(long)orow * 64 + prow]      = acc0[r];
        out[(long)orow * 64 + 32 + prow] = acc1[r];
    }
}

extern "C" void kernel_launch(void* const* d_in, const int* in_sizes, int n_in,
                              void* d_out, int out_size, void* d_ws, size_t ws_size,
                              hipStream_t stream) {
    const float* inst   = (const float*)d_in[0]; // (B,G,64)
    const float* anchor = (const float*)d_in[1]; // (B,G,2)
    const float* W      = (const float*)d_in[2]; // (3,3,64,64)
    float* out = (float*)d_out;

    char* ws = (char*)d_ws;
    float*     s0a  = (float*)(ws);                      // 512 KB
    float*     s1a  = (float*)(ws + 524288);             // 512 KB
    int*       pidx = (int*)(ws + 1048576);              // 512 KB
    int*       grd  = (int*)(ws + 1572864);              // 1 MB
    float2*    bmin = (float2*)(ws + 2621440);           // 2 KB
    _Float16*  fb   = (_Float16*)(ws + 2625536);         // (N+1)*64 f16 = 16.78 MB
    _Float16*  bpk  = (_Float16*)(ws + 19402880);        // 72 KB

    k_cvt  <<<2048, 256, 0, stream>>>(inst, fb, grd);    // clears grd (no memset!)
    k_wpack<<<18,   256, 0, stream>>>(W, bpk);
    k_sig  <<<256,  256, 0, stream>>>(anchor, s0a, s1a, bmin);
    k_grid <<<512,  256, 0, stream>>>(s0a, s1a, bmin, pidx, grd);
    k_mconv<<<1024, 256, 0, stream>>>(fb, bpk, pidx, grd, out);
}

// Round 6
// 55.399 us; speedup vs baseline: 3.6145x; 1.0781x over previous
//
#include <hip/hip_runtime.h>

#define NPTS  131072        // B*G
#define GPTS  32768         // G

typedef __attribute__((ext_vector_type(4)))  _Float16 half4v;
typedef __attribute__((ext_vector_type(8)))  _Float16 half8v;
typedef __attribute__((ext_vector_type(16))) float    f32x16;

// ---- sigmoid emulating the reference f32 pipeline (bit-faithful) ----------
__device__ __forceinline__ float sigf(float x) {
    x = fminf(fmaxf(x, -9.21f), 9.21f);
    float t = (float)exp(-(double)x);
    return 1.0f / (1.0f + t);
}

// ---- fused front-end -------------------------------------------------------
// blocks [0,512):    sigmoid + per-block min + grid clear (latency-bound, first)
// blocks [512,530):  W -> 32x32x16 f16 B-fragments
// blocks [530,2578): feats f32 -> f16 rows (+1 zero row)  (BW-bound, hides sig)
__global__ __launch_bounds__(256) void k_front(const float* __restrict__ anchor,
                                               const float* __restrict__ W,
                                               const float* __restrict__ feats,
                                               float* __restrict__ s0a,
                                               float* __restrict__ s1a,
                                               float2* __restrict__ blockmin,
                                               _Float16* __restrict__ bpk,
                                               _Float16* __restrict__ fb,
                                               int* __restrict__ grd) {
    const int bid = blockIdx.x;
    if (bid < 512) {
        __shared__ float red[8];
        int i = bid * 256 + threadIdx.x;            // [0,131072)
        int2 mone = {-1, -1};
        ((int2*)grd)[i] = mone;                     // clear 1 MB rulebook grid
        float2 a = ((const float2*)anchor)[i];
        float s0 = sigf(a.x);
        float s1 = sigf(a.y);
        s0a[i] = s0;
        s1a[i] = s1;
        float m0 = s0, m1 = s1;
        #pragma unroll
        for (int off = 32; off; off >>= 1) {
            m0 = fminf(m0, __shfl_down(m0, off));
            m1 = fminf(m1, __shfl_down(m1, off));
        }
        int wv = threadIdx.x >> 6;
        if ((threadIdx.x & 63) == 0) { red[wv * 2] = m0; red[wv * 2 + 1] = m1; }
        __syncthreads();
        if (threadIdx.x == 0) {
            float a0 = fminf(fminf(red[0], red[2]), fminf(red[4], red[6]));
            float a1 = fminf(fminf(red[1], red[3]), fminf(red[5], red[7]));
            blockmin[bid] = make_float2(a0, a1);
        }
    } else if (bid < 530) {
        // frag q = t*8 + ks*2 + nt; lane l: B[k=ks*16+(l>>5)*8+j][n=nt*32+(l&31)]
        int tid = (bid - 512) * 256 + threadIdx.x;
        if (tid >= 4608) return;
        int l  = tid & 63;
        int q  = tid >> 6;
        int nt = q & 1;
        int ks = (q >> 1) & 3;
        int t  = q >> 3;
        int n  = nt * 32 + (l & 31);
        int kb = ks * 16 + (l >> 5) * 8;
        half8v v;
        #pragma unroll
        for (int j = 0; j < 8; ++j)
            v[j] = (_Float16)W[(t * 64 + kb + j) * 64 + n];
        ((half8v*)bpk)[q * 64 + l] = v;
    } else {
        int tid = (bid - 530) * 256 + threadIdx.x;  // [0,524288)
        if (bid == 530 && threadIdx.x < 8) {        // zero row NPTS
            half8v z = {};
            *(half8v*)(fb + (long)NPTS * 64 + threadIdx.x * 8) = z;
        }
        #pragma unroll
        for (int r = 0; r < 4; ++r) {
            long i = tid + (long)r * 524288;        // 2,097,152 float4 total
            float4 f = ((const float4*)feats)[i];
            half4v o = {(_Float16)f.x, (_Float16)f.y, (_Float16)f.z, (_Float16)f.w};
            *(half4v*)(fb + i * 4) = o;
        }
    }
}

// ---- cell index + rulebook scatter (max id wins); min-fold at head --------
__global__ __launch_bounds__(256) void k_grid(const float* __restrict__ s0a,
                                              const float* __restrict__ s1a,
                                              const float2* __restrict__ blockmin,
                                              int* __restrict__ pidx,
                                              int* __restrict__ grid) {
    __shared__ float red[8];
    float2 ba = blockmin[threadIdx.x];
    float2 bb = blockmin[threadIdx.x + 256];
    float m0 = fminf(ba.x, bb.x), m1 = fminf(ba.y, bb.y);
    #pragma unroll
    for (int off = 32; off; off >>= 1) {
        m0 = fminf(m0, __shfl_down(m0, off));
        m1 = fminf(m1, __shfl_down(m1, off));
    }
    int wv = threadIdx.x >> 6;
    if ((threadIdx.x & 63) == 0) { red[wv * 2] = m0; red[wv * 2 + 1] = m1; }
    __syncthreads();
    m0 = fminf(fminf(red[0], red[2]), fminf(red[4], red[6]));
    m1 = fminf(fminf(red[1], red[3]), fminf(red[5], red[7]));

    int i = blockIdx.x * 256 + threadIdx.x;
    int iy = (int)((s0a[i] - m0) * 256.0f);
    int ix = (int)((s1a[i] - m1) * 256.0f);
    pidx[i] = (iy << 8) | ix;
    int b = i >> 15;
    atomicMax(&grid[(b << 16) + (iy << 8) + ix], i);
}

// ---- MFMA conv: wave = 32 points x 64 couts, f16 single pass --------------
// A-frag: lane l holds A[row=l&31][k=ks*16+(l>>5)*8+j] -> 16B load from row
// C/D: col=lane&31, row=(reg&3)+8*(reg>>2)+4*(lane>>5)   [HW-verified]
__global__ __launch_bounds__(256, 4) void k_mconv(const _Float16* __restrict__ fb,
                                                  const _Float16* __restrict__ bpk,
                                                  const int* __restrict__ pidx,
                                                  const int* __restrict__ grid,
                                                  float* __restrict__ out) {
    const int lane  = threadIdx.x & 63;
    const int wv    = threadIdx.x >> 6;
    const int pbase = (blockIdx.x << 7) + (wv << 5);
    const int prow  = lane & 31;
    const int khalf = lane >> 5;
    const int p     = pbase + prow;

    const int pk = pidx[p];
    const int iy = pk >> 8;
    const int ix = pk & 255;
    const int* gb = grid + ((p >> 15) << 16);

    int nid[9];
    #pragma unroll
    for (int t = 0; t < 9; ++t) {
        const int ny = iy + t / 3 - 1;
        const int nx = ix + t % 3 - 1;
        int n = ((unsigned)ny < 256u && (unsigned)nx < 256u) ? gb[(ny << 8) + nx] : -1;
        nid[t] = (n < 0) ? NPTS : n;               // zero row for invalid taps
    }

    const half8v* bq = (const half8v*)bpk + lane;

    f32x16 acc0, acc1;
    #pragma unroll
    for (int r = 0; r < 16; ++r) { acc0[r] = 0.0f; acc1[r] = 0.0f; }

    #pragma unroll
    for (int t = 0; t < 9; ++t) {
        const half8v* arow = (const half8v*)(fb + ((long)nid[t] << 6));
        half8v a0 = arow[khalf];
        half8v a1 = arow[2 + khalf];
        half8v a2 = arow[4 + khalf];
        half8v a3 = arow[6 + khalf];
        const half8v* bt = bq + (t << 9);          // 8 frags * 64 lanes per tap
        acc0 = __builtin_amdgcn_mfma_f32_32x32x16_f16(a0, bt[0 * 64], acc0, 0, 0, 0);
        acc1 = __builtin_amdgcn_mfma_f32_32x32x16_f16(a0, bt[1 * 64], acc1, 0, 0, 0);
        acc0 = __builtin_amdgcn_mfma_f32_32x32x16_f16(a1, bt[2 * 64], acc0, 0, 0, 0);
        acc1 = __builtin_amdgcn_mfma_f32_32x32x16_f16(a1, bt[3 * 64], acc1, 0, 0, 0);
        acc0 = __builtin_amdgcn_mfma_f32_32x32x16_f16(a2, bt[4 * 64], acc0, 0, 0, 0);
        acc1 = __builtin_amdgcn_mfma_f32_32x32x16_f16(a2, bt[5 * 64], acc1, 0, 0, 0);
        acc0 = __builtin_amdgcn_mfma_f32_32x32x16_f16(a3, bt[6 * 64], acc0, 0, 0, 0);
        acc1 = __builtin_amdgcn_mfma_f32_32x32x16_f16(a3, bt[7 * 64], acc1, 0, 0, 0);
    }

    #pragma unroll
    for (int r = 0; r < 16; ++r) {
        int orow = pbase + (r & 3) + ((r >> 2) << 3) + (khalf << 2);
        out[(long)orow * 64 + prow]      = acc0[r];
        out[(long)orow * 64 + 32 + prow] = acc1[r];
    }
}

extern "C" void kernel_launch(void* const* d_in, const int* in_sizes, int n_in,
                              void* d_out, int out_size, void* d_ws, size_t ws_size,
                              hipStream_t stream) {
    const float* inst   = (const float*)d_in[0]; // (B,G,64)
    const float* anchor = (const float*)d_in[1]; // (B,G,2)
    const float* W      = (const float*)d_in[2]; // (3,3,64,64)
    float* out = (float*)d_out;

    char* ws = (char*)d_ws;
    float*     s0a  = (float*)(ws);                      // 512 KB
    float*     s1a  = (float*)(ws + 524288);             // 512 KB
    int*       pidx = (int*)(ws + 1048576);              // 512 KB
    int*       grd  = (int*)(ws + 1572864);              // 1 MB
    float2*    bmin = (float2*)(ws + 2621440);           // 4 KB (512 float2)
    _Float16*  fb   = (_Float16*)(ws + 2625536);         // (N+1)*64 f16
    _Float16*  bpk  = (_Float16*)(ws + 19402880);        // 72 KB

    k_front<<<2578, 256, 0, stream>>>(anchor, W, inst, s0a, s1a, bmin, bpk, fb, grd);
    k_grid <<<512,  256, 0, stream>>>(s0a, s1a, bmin, pidx, grd);
    k_mconv<<<1024, 256, 0, stream>>>(fb, bpk, pidx, grd, out);
}